// Round 1
// baseline (130.821 us; speedup 1.0000x reference)
//
#include <hip/hip_runtime.h>
#include <math.h>

// Problem: B=16, T=2048, D=256, gamma=0.9
// out[b,t,d] = S2[t,d] * (x@Wq)[b,t,d]
// S2[t,d] = S[8d + (t>>8)][t&255]   (reshape-scramble)
// S[t>=1] = A[t], S[0] = A[1],  A[t] = gamma*A[t-1] + g[t], A[0]=0 (g[0] := 0)
// g = y @ Wk,  y[t,:] = sum_b w[b,t]*x[b,t,:],  w[b,t] = x[b,t,:] . rowsum(Wv)
//
// R9: (1) k_y also emits xbf (bf16 x) so k_qgemm is a pure bf16 GEMM staged
// via global_load_lds_dwordx4 (kills the 640-VALU/thread f2bf storm);
// (2) k_S2P rewritten: incremental chunk-prefix (16x less work), LDS
// transpose, coalesced float4 S2 writes (was 64-way scattered 4B stores).
// 5 kernels: prep -> y -> gs -> S2P -> qgemm.

#define GAMMA_F 0.9f
#define T_LEN 2048
#define D_DIM 256
#define B_DIM 16

typedef __attribute__((ext_vector_type(8))) short bf16x8;
typedef __attribute__((ext_vector_type(16))) float f32x16;

__device__ inline ushort f2bf(float f) {
    union { float f; unsigned u; } v; v.f = f;
    unsigned r = (v.u + 0x7FFFu + ((v.u >> 16) & 1u)) >> 16;  // RNE
    return (ushort)r;
}

// async global->LDS, 16B per lane; LDS dest = wave-uniform base + lane*16
__device__ __forceinline__ void gload_lds16(const void* g, void* l) {
    __builtin_amdgcn_global_load_lds(
        (const __attribute__((address_space(1))) unsigned int*)g,
        (__attribute__((address_space(3))) unsigned int*)l, 16, 0, 0);
}

// ---------- K1: prep — WqT, WkT (bf16 [n][k]) + wv_sum ----------
__global__ __launch_bounds__(256) void k_prep(const float* __restrict__ Wq,
                                              const float* __restrict__ Wk,
                                              const float* __restrict__ Wv,
                                              ushort* __restrict__ WqT,
                                              ushort* __restrict__ WkT,
                                              float* __restrict__ wv_sum) {
    int bid = blockIdx.x;
    int tid = threadIdx.x;
    if (bid < 32) {
        __shared__ float tile[64][68];
        const float* W = (bid < 16) ? Wq : Wk;
        ushort* WT = (bid < 16) ? WqT : WkT;
        int b = bid & 15;
        int k0 = (b & 3) * 64;
        int n0 = (b >> 2) * 64;
        int r = tid >> 4;            // 0..15
        int c4 = (tid & 15) * 4;     // 0..60
#pragma unroll
        for (int i = 0; i < 4; ++i) {
            float4 v = *(const float4*)(W + (size_t)(k0 + r + 16 * i) * D_DIM + n0 + c4);
            *(float4*)&tile[r + 16 * i][c4] = v;
        }
        __syncthreads();
        int n = tid >> 2;            // 0..63
        int j0 = (tid & 3) * 16;     // 0..48
        ushort tmp[16];
#pragma unroll
        for (int i = 0; i < 16; ++i) tmp[i] = f2bf(tile[j0 + i][n]);
        ushort* dst = WT + (size_t)(n0 + n) * D_DIM + k0 + j0;
#pragma unroll
        for (int i = 0; i < 16; ++i) dst[i] = tmp[i];
    } else {
        int j = (bid - 32) * 64 + (tid >> 2);
        int q = tid & 3;
        const float4* row4 = (const float4*)(Wv + (size_t)j * D_DIM + q * 64);
        float s = 0.f;
#pragma unroll
        for (int i = 0; i < 16; ++i) {
            float4 v = row4[i];
            s += v.x + v.y + v.z + v.w;
        }
        s += __shfl_xor(s, 1, 64);
        s += __shfl_xor(s, 2, 64);
        if (q == 0) wv_sum[j] = s;
    }
}

// ---------- K2: y (bf16) + xbf (bf16 copy of x) — single streaming pass ----------
__global__ __launch_bounds__(256) void k_y(const float* __restrict__ x,
                                           const float* __restrict__ wv_sum,
                                           ushort* __restrict__ ybf,
                                           ushort* __restrict__ xbf) {
    int t = blockIdx.x;
    int d = threadIdx.x;
    float wvd = wv_sum[d];
    float xr[B_DIM];
#pragma unroll
    for (int b = 0; b < B_DIM; ++b)
        xr[b] = x[((size_t)b * T_LEN + t) * D_DIM + d];

    // bf16 copy for the Q-GEMM (removes f32 read + inline cvt there)
#pragma unroll
    for (int b = 0; b < B_DIM; ++b)
        xbf[((size_t)b * T_LEN + t) * D_DIM + d] = f2bf(xr[b]);

    __shared__ float red[B_DIM][4];
    int wave = d >> 6, lane = d & 63;
#pragma unroll
    for (int b = 0; b < B_DIM; ++b) {
        float p = xr[b] * wvd;
        for (int o = 32; o > 0; o >>= 1) p += __shfl_down(p, o, 64);
        if (lane == 0) red[b][wave] = p;
    }
    __syncthreads();
    float yv = 0.f;
#pragma unroll
    for (int b = 0; b < B_DIM; ++b) {
        float wb = red[b][0] + red[b][1] + red[b][2] + red[b][3];
        yv += wb * xr[b];
    }
    ybf[(size_t)t * D_DIM + d] = f2bf(yv);
}

// ---------- K3: fused g-GEMM + local scan (128 blocks) ----------
__global__ __launch_bounds__(256) void k_gs(const ushort* __restrict__ ybf,
                                            const ushort* __restrict__ WkT,
                                            float* __restrict__ loc,
                                            float* __restrict__ carry) {
    __shared__ ushort As[32 * 64 * 8];   // 32 KB  [s2h][row^swz][8]
    __shared__ ushort Bs[32 * 64 * 8];   // 32 KB
    float* Cs = (float*)As;              // 16 KB alias: [tl=0..63][dl=0..63]
    int mt = blockIdx.x >> 2;            // 0..31 (t tile)
    int nt = blockIdx.x & 3;             // 0..3  (n tile)
    int tid = threadIdx.x, lane = tid & 63, w = tid >> 6;
    int wr = w >> 1, wc = w & 1, l31 = lane & 31, lh = lane >> 5;

#pragma unroll
    for (int i = 0; i < 8; ++i) {
        int slot = tid + 256 * i;        // 0..2047
        int r = slot >> 5;               // 0..63
        int s2h = slot & 31;             // 0..31
        int rs = r ^ (s2h & 7);          // bank swizzle
        *(bf16x8*)&As[(s2h * 64 + rs) * 8] =
            *(const bf16x8*)&ybf[(size_t)(mt * 64 + r) * D_DIM + s2h * 8];
        *(bf16x8*)&Bs[(s2h * 64 + rs) * 8] =
            *(const bf16x8*)&WkT[(size_t)(nt * 64 + r) * D_DIM + s2h * 8];
    }
    __syncthreads();

    f32x16 acc;
#pragma unroll
    for (int e = 0; e < 16; ++e) acc[e] = 0.f;
#pragma unroll
    for (int s = 0; s < 16; ++s) {
        int s2h = s * 2 + lh;
        int ra = (wr * 32 + l31) ^ (s2h & 7);
        int rb = (wc * 32 + l31) ^ (s2h & 7);
        bf16x8 a = *(bf16x8*)&As[(s2h * 64 + ra) * 8];
        bf16x8 b = *(bf16x8*)&Bs[(s2h * 64 + rb) * 8];
        acc = __builtin_amdgcn_mfma_f32_32x32x16_bf16(a, b, acc, 0, 0, 0);
    }
    __syncthreads();                     // all As/Bs reads done; alias Cs

#pragma unroll
    for (int reg = 0; reg < 16; ++reg) {
        int rr = (reg & 3) + 8 * (reg >> 2) + 4 * lh;
        Cs[(wr * 32 + rr) * 64 + wc * 32 + l31] = acc[reg];
    }
    __syncthreads();

    // scan: 512 (cl, dl) tasks over 256 threads
#pragma unroll
    for (int half = 0; half < 2; ++half) {
        int task = half * 256 + tid;     // 0..511
        int dl = task & 63;              // 0..63
        int cl = task >> 6;              // 0..7
        float a = 0.f;
#pragma unroll
        for (int j = 0; j < 8; ++j) {
            int tl = cl * 8 + j;
            int gt = mt * 64 + tl;
            float v = (gt == 0) ? 0.f : Cs[tl * 64 + dl];
            a = GAMMA_F * a + v;
            loc[(size_t)gt * D_DIM + nt * 64 + dl] = a;
        }
        carry[(size_t)(mt * 8 + cl) * D_DIM + nt * 64 + dl] = a;
    }
}

// ---------- K4: S2 scatter, rebuilt. Block (o, dseg): 256 rows x 32 cols of S2.
// Thread r keeps incremental chunk-prefix p_d = sum_j g8^(d-1-j) carry[j][r]
// (32-chunk warm-up once per segment; >= old 32-term truncation accuracy).
// S2[(o<<8)+r][d] = loc[8d+o][r] + g^(o+1)*p_d ; tile through LDS -> float4 writes.
__global__ __launch_bounds__(256) void k_S2P(const float* __restrict__ loc,
                                             const float* __restrict__ carry,
                                             float* __restrict__ S2) {
    __shared__ float Ls[256][33];           // +1 pad: conflict-free column writes
    int o = blockIdx.x >> 3;                // 0..7
    int dseg = blockIdx.x & 7;              // 0..7
    int r = threadIdx.x;                    // 0..255
    int dstart = dseg * 32;
    const float g8 = 0.43046721f;           // 0.9^8
    const float log2g = -0.15200309344504995f;  // log2(0.9)
    float gp = exp2f((float)(o + 1) * log2g);

    // warm-up: 32 chunks before the segment (g8^32 ~ 2e-12: exact to f32)
    float p = 0.f;
    int j0 = dstart - 32; if (j0 < 0) j0 = 0;
    for (int j = j0; j < dstart; ++j)
        p = p * g8 + carry[(size_t)j * D_DIM + r];

#pragma unroll
    for (int dd = 0; dd < 32; ++dd) {
        int d_ = dstart + dd;
        float Aval = loc[(size_t)(8 * d_ + o) * D_DIM + r] + gp * p;
        if (o == 0 && d_ == 0) Aval = loc[D_DIM + r];   // S[0] = A[1] (p=0, src=1)
        Ls[r][dd] = Aval;
        p = p * g8 + carry[(size_t)d_ * D_DIM + r];
    }
    __syncthreads();

    // transpose out: thread (rr,cq) writes float4 at S2[(o<<8)+row][dstart+cq*4]
    int rr = threadIdx.x >> 3;              // 0..31
    int cq = threadIdx.x & 7;               // 0..7
#pragma unroll
    for (int it = 0; it < 8; ++it) {
        int row = it * 32 + rr;
        float4 v;
        v.x = Ls[row][cq * 4 + 0];
        v.y = Ls[row][cq * 4 + 1];
        v.z = Ls[row][cq * 4 + 2];
        v.w = Ls[row][cq * 4 + 3];
        *(float4*)&S2[(size_t)((o << 8) + row) * D_DIM + dstart + cq * 4] = v;
    }
}

// ---------- K5: out = (xbf @ WqT^T) * S2 — pure bf16 GEMM, async LDS staging ----------
__global__ __launch_bounds__(256) void k_qgemm(const ushort* __restrict__ xbf,
                                               const ushort* __restrict__ WqT,
                                               const float* __restrict__ S2,
                                               float* __restrict__ out) {
    __shared__ ushort As[8 * 128 * 8];   // 16 KB  [kk][row][8]
    __shared__ ushort Bs[8 * 128 * 8];   // 16 KB
    int bid = blockIdx.x;
    int mb = bid >> 1;           // 0..255  (M tile)
    int nb = bid & 1;            // 0..1    (N tile)
    int tid = threadIdx.x;
    int lane = tid & 63, w = tid >> 6;
    int wr = w >> 1, wc = w & 1;
    int l31 = lane & 31, lh = lane >> 5;

    f32x16 acc[2][2];
#pragma unroll
    for (int i = 0; i < 2; ++i)
#pragma unroll
        for (int j = 0; j < 2; ++j)
#pragma unroll
            for (int e = 0; e < 16; ++e) acc[i][j][e] = 0.f;

    const ushort* ab = xbf + (size_t)mb * 128 * D_DIM;
    const ushort* bb = WqT + (size_t)nb * 128 * D_DIM;

    for (int kb = 0; kb < 4; ++kb) {
#pragma unroll
        for (int i = 0; i < 4; ++i) {
            int slot = i * 256 + tid;            // 0..1023 = kk*128 + row
            int kk = slot >> 7;
            int row = slot & 127;
            int ldsbase = (i * 256 + w * 64) * 8;  // wave-uniform; HW adds lane*16B
            gload_lds16(ab + (size_t)row * D_DIM + kb * 64 + kk * 8, &As[ldsbase]);
            gload_lds16(bb + (size_t)row * D_DIM + kb * 64 + kk * 8, &Bs[ldsbase]);
        }
        __syncthreads();
#pragma unroll
        for (int s = 0; s < 4; ++s) {
            int c0 = (s * 2 + lh) * 128;
            bf16x8 a0 = *(bf16x8*)&As[(c0 + wr * 64 + l31) * 8];
            bf16x8 a1 = *(bf16x8*)&As[(c0 + wr * 64 + 32 + l31) * 8];
            bf16x8 b0 = *(bf16x8*)&Bs[(c0 + wc * 64 + l31) * 8];
            bf16x8 b1 = *(bf16x8*)&Bs[(c0 + wc * 64 + 32 + l31) * 8];
            acc[0][0] = __builtin_amdgcn_mfma_f32_32x32x16_bf16(a0, b0, acc[0][0], 0, 0, 0);
            acc[0][1] = __builtin_amdgcn_mfma_f32_32x32x16_bf16(a0, b1, acc[0][1], 0, 0, 0);
            acc[1][0] = __builtin_amdgcn_mfma_f32_32x32x16_bf16(a1, b0, acc[1][0], 0, 0, 0);
            acc[1][1] = __builtin_amdgcn_mfma_f32_32x32x16_bf16(a1, b1, acc[1][1], 0, 0, 0);
        }
        __syncthreads();
    }

    int t_base = (mb & 15) * 128;
    size_t row_base = (size_t)mb * 128;
#pragma unroll
    for (int mi = 0; mi < 2; ++mi) {
#pragma unroll
        for (int ni = 0; ni < 2; ++ni) {
            int gn = nb * 128 + wc * 64 + ni * 32 + l31;
#pragma unroll
            for (int reg = 0; reg < 16; ++reg) {
                int rr = (reg & 3) + 8 * (reg >> 2) + 4 * lh;
                int m = wr * 64 + mi * 32 + rr;
                float s2v = S2[(size_t)(t_base + m) * D_DIM + gn];
                out[(row_base + m) * D_DIM + gn] = acc[mi][ni][reg] * s2v;
            }
        }
    }
}

extern "C" void kernel_launch(void* const* d_in, const int* in_sizes, int n_in,
                              void* d_out, int out_size, void* d_ws, size_t ws_size,
                              hipStream_t stream) {
    const float* x  = (const float*)d_in[0];
    const float* Wq = (const float*)d_in[1];
    const float* Wk = (const float*)d_in[2];
    const float* Wv = (const float*)d_in[3];
    float* out = (float*)d_out;

    // workspace layout
    float* ws = (float*)d_ws;
    float* loc    = ws;                        // 524288 f
    float* S2     = loc + 524288;              // 524288 f
    float* wv_sum = S2 + 524288;               // 256 f
    float* carry  = wv_sum + 256;              // 65536 f (256 chunks x 256)
    ushort* WqT   = (ushort*)(carry + 65536);  // 65536 us
    ushort* WkT   = WqT + 65536;               // 65536 us
    ushort* ybf   = WkT + 65536;               // 524288 us
    ushort* xbf   = ybf + 524288;              // 8388608 us (16 MB)

    k_prep<<<36, 256, 0, stream>>>(Wq, Wk, Wv, WqT, WkT, wv_sum);
    k_y<<<T_LEN, 256, 0, stream>>>(x, wv_sum, ybf, xbf);
    k_gs<<<128, 256, 0, stream>>>(ybf, WkT, loc, carry);
    k_S2P<<<64, 256, 0, stream>>>(loc, carry, S2);
    k_qgemm<<<(B_DIM * T_LEN / 128) * 2, 256, 0, stream>>>(xbf, WqT, S2, out);
}

// Round 2
// 122.451 us; speedup vs baseline: 1.0684x; 1.0684x over previous
//
#include <hip/hip_runtime.h>
#include <math.h>

// Problem: B=16, T=2048, D=256, gamma=0.9
// out[b,t,d] = S2[t,d] * (x@Wq)[b,t,d]
// S2[t,d] = S[8d + (t>>8)][t&255]   (reshape-scramble)
// S[t>=1] = A[t], S[0] = A[1],  A[t] = gamma*A[t-1] + g[t], A[0]=0 (g[0] := 0)
// g = y @ Wk,  y[t,:] = sum_b w[b,t]*x[b,t,:],  w[b,t] = x[b,t,:] . rowsum(Wv)
//
// R10: (1) k_y rebuilt wave-local: lane owns 4 d (float4), batch-dot via
// in-wave shfl_xor butterfly — no LDS, no barriers, 4x fewer mem instrs;
// (2) k_qgemm 2-phase LDS double-buffer: stage k+1 before MFMA of k,
// one barrier per K-step (was two full vmcnt(0) drains).
// 5 kernels: prep -> y -> gs -> S2P -> qgemm.

#define GAMMA_F 0.9f
#define T_LEN 2048
#define D_DIM 256
#define B_DIM 16

typedef __attribute__((ext_vector_type(8))) short bf16x8;
typedef __attribute__((ext_vector_type(16))) float f32x16;

__device__ inline ushort f2bf(float f) {
    union { float f; unsigned u; } v; v.f = f;
    unsigned r = (v.u + 0x7FFFu + ((v.u >> 16) & 1u)) >> 16;  // RNE
    return (ushort)r;
}

// async global->LDS, 16B per lane; LDS dest = wave-uniform base + lane*16
__device__ __forceinline__ void gload_lds16(const void* g, void* l) {
    __builtin_amdgcn_global_load_lds(
        (const __attribute__((address_space(1))) unsigned int*)g,
        (__attribute__((address_space(3))) unsigned int*)l, 16, 0, 0);
}

// ---------- K1: prep — WqT, WkT (bf16 [n][k]) + wv_sum ----------
__global__ __launch_bounds__(256) void k_prep(const float* __restrict__ Wq,
                                              const float* __restrict__ Wk,
                                              const float* __restrict__ Wv,
                                              ushort* __restrict__ WqT,
                                              ushort* __restrict__ WkT,
                                              float* __restrict__ wv_sum) {
    int bid = blockIdx.x;
    int tid = threadIdx.x;
    if (bid < 32) {
        __shared__ float tile[64][68];
        const float* W = (bid < 16) ? Wq : Wk;
        ushort* WT = (bid < 16) ? WqT : WkT;
        int b = bid & 15;
        int k0 = (b & 3) * 64;
        int n0 = (b >> 2) * 64;
        int r = tid >> 4;            // 0..15
        int c4 = (tid & 15) * 4;     // 0..60
#pragma unroll
        for (int i = 0; i < 4; ++i) {
            float4 v = *(const float4*)(W + (size_t)(k0 + r + 16 * i) * D_DIM + n0 + c4);
            *(float4*)&tile[r + 16 * i][c4] = v;
        }
        __syncthreads();
        int n = tid >> 2;            // 0..63
        int j0 = (tid & 3) * 16;     // 0..48
        ushort tmp[16];
#pragma unroll
        for (int i = 0; i < 16; ++i) tmp[i] = f2bf(tile[j0 + i][n]);
        ushort* dst = WT + (size_t)(n0 + n) * D_DIM + k0 + j0;
#pragma unroll
        for (int i = 0; i < 16; ++i) dst[i] = tmp[i];
    } else {
        int j = (bid - 32) * 64 + (tid >> 2);
        int q = tid & 3;
        const float4* row4 = (const float4*)(Wv + (size_t)j * D_DIM + q * 64);
        float s = 0.f;
#pragma unroll
        for (int i = 0; i < 16; ++i) {
            float4 v = row4[i];
            s += v.x + v.y + v.z + v.w;
        }
        s += __shfl_xor(s, 1, 64);
        s += __shfl_xor(s, 2, 64);
        if (q == 0) wv_sum[j] = s;
    }
}

// ---------- K2: y (bf16) + xbf — wave-local, float4, no LDS, no barriers ----------
// Wave covers D=256 (lane owns d = 4*lane..4*lane+3). 4 t per block.
__global__ __launch_bounds__(256) void k_y(const float* __restrict__ x,
                                           const float* __restrict__ wv_sum,
                                           ushort* __restrict__ ybf,
                                           ushort* __restrict__ xbf) {
    int tid = threadIdx.x;
    int lane = tid & 63;
    int t = blockIdx.x * 4 + (tid >> 6);
    int d0 = lane * 4;
    float4 wv4 = *(const float4*)(wv_sum + d0);

    float4 xr[B_DIM];
    float w[B_DIM];
#pragma unroll
    for (int b = 0; b < B_DIM; ++b) {
        xr[b] = *(const float4*)(x + ((size_t)b * T_LEN + t) * D_DIM + d0);
        float p = xr[b].x * wv4.x + xr[b].y * wv4.y + xr[b].z * wv4.z + xr[b].w * wv4.w;
#pragma unroll
        for (int o = 32; o > 0; o >>= 1) p += __shfl_xor(p, o, 64);
        w[b] = p;   // full-batch dot, broadcast to all lanes
    }

    float4 acc = make_float4(0.f, 0.f, 0.f, 0.f);
#pragma unroll
    for (int b = 0; b < B_DIM; ++b) {
        acc.x += w[b] * xr[b].x;
        acc.y += w[b] * xr[b].y;
        acc.z += w[b] * xr[b].z;
        acc.w += w[b] * xr[b].w;
        ushort4 s;
        s.x = f2bf(xr[b].x); s.y = f2bf(xr[b].y);
        s.z = f2bf(xr[b].z); s.w = f2bf(xr[b].w);
        *(ushort4*)&xbf[((size_t)b * T_LEN + t) * D_DIM + d0] = s;
    }
    ushort4 ys;
    ys.x = f2bf(acc.x); ys.y = f2bf(acc.y);
    ys.z = f2bf(acc.z); ys.w = f2bf(acc.w);
    *(ushort4*)&ybf[(size_t)t * D_DIM + d0] = ys;
}

// ---------- K3: fused g-GEMM + local scan (128 blocks) ----------
__global__ __launch_bounds__(256) void k_gs(const ushort* __restrict__ ybf,
                                            const ushort* __restrict__ WkT,
                                            float* __restrict__ loc,
                                            float* __restrict__ carry) {
    __shared__ ushort As[32 * 64 * 8];   // 32 KB  [s2h][row^swz][8]
    __shared__ ushort Bs[32 * 64 * 8];   // 32 KB
    float* Cs = (float*)As;              // 16 KB alias: [tl=0..63][dl=0..63]
    int mt = blockIdx.x >> 2;            // 0..31 (t tile)
    int nt = blockIdx.x & 3;             // 0..3  (n tile)
    int tid = threadIdx.x, lane = tid & 63, w = tid >> 6;
    int wr = w >> 1, wc = w & 1, l31 = lane & 31, lh = lane >> 5;

#pragma unroll
    for (int i = 0; i < 8; ++i) {
        int slot = tid + 256 * i;        // 0..2047
        int r = slot >> 5;               // 0..63
        int s2h = slot & 31;             // 0..31
        int rs = r ^ (s2h & 7);          // bank swizzle
        *(bf16x8*)&As[(s2h * 64 + rs) * 8] =
            *(const bf16x8*)&ybf[(size_t)(mt * 64 + r) * D_DIM + s2h * 8];
        *(bf16x8*)&Bs[(s2h * 64 + rs) * 8] =
            *(const bf16x8*)&WkT[(size_t)(nt * 64 + r) * D_DIM + s2h * 8];
    }
    __syncthreads();

    f32x16 acc;
#pragma unroll
    for (int e = 0; e < 16; ++e) acc[e] = 0.f;
#pragma unroll
    for (int s = 0; s < 16; ++s) {
        int s2h = s * 2 + lh;
        int ra = (wr * 32 + l31) ^ (s2h & 7);
        int rb = (wc * 32 + l31) ^ (s2h & 7);
        bf16x8 a = *(bf16x8*)&As[(s2h * 64 + ra) * 8];
        bf16x8 b = *(bf16x8*)&Bs[(s2h * 64 + rb) * 8];
        acc = __builtin_amdgcn_mfma_f32_32x32x16_bf16(a, b, acc, 0, 0, 0);
    }
    __syncthreads();                     // all As/Bs reads done; alias Cs

#pragma unroll
    for (int reg = 0; reg < 16; ++reg) {
        int rr = (reg & 3) + 8 * (reg >> 2) + 4 * lh;
        Cs[(wr * 32 + rr) * 64 + wc * 32 + l31] = acc[reg];
    }
    __syncthreads();

    // scan: 512 (cl, dl) tasks over 256 threads
#pragma unroll
    for (int half = 0; half < 2; ++half) {
        int task = half * 256 + tid;     // 0..511
        int dl = task & 63;              // 0..63
        int cl = task >> 6;              // 0..7
        float a = 0.f;
#pragma unroll
        for (int j = 0; j < 8; ++j) {
            int tl = cl * 8 + j;
            int gt = mt * 64 + tl;
            float v = (gt == 0) ? 0.f : Cs[tl * 64 + dl];
            a = GAMMA_F * a + v;
            loc[(size_t)gt * D_DIM + nt * 64 + dl] = a;
        }
        carry[(size_t)(mt * 8 + cl) * D_DIM + nt * 64 + dl] = a;
    }
}

// ---------- K4: S2 build. Block (o, dseg): 256 rows x 32 cols of S2. ----------
__global__ __launch_bounds__(256) void k_S2P(const float* __restrict__ loc,
                                             const float* __restrict__ carry,
                                             float* __restrict__ S2) {
    __shared__ float Ls[256][33];           // +1 pad: conflict-free column writes
    int o = blockIdx.x >> 3;                // 0..7
    int dseg = blockIdx.x & 7;              // 0..7
    int r = threadIdx.x;                    // 0..255
    int dstart = dseg * 32;
    const float g8 = 0.43046721f;           // 0.9^8
    const float log2g = -0.15200309344504995f;  // log2(0.9)
    float gp = exp2f((float)(o + 1) * log2g);

    // warm-up: 32 chunks before the segment (g8^32 ~ 2e-12: exact to f32)
    float p = 0.f;
    int j0 = dstart - 32; if (j0 < 0) j0 = 0;
    for (int j = j0; j < dstart; ++j)
        p = p * g8 + carry[(size_t)j * D_DIM + r];

#pragma unroll
    for (int dd = 0; dd < 32; ++dd) {
        int d_ = dstart + dd;
        float Aval = loc[(size_t)(8 * d_ + o) * D_DIM + r] + gp * p;
        if (o == 0 && d_ == 0) Aval = loc[D_DIM + r];   // S[0] = A[1] (p=0, src=1)
        Ls[r][dd] = Aval;
        p = p * g8 + carry[(size_t)d_ * D_DIM + r];
    }
    __syncthreads();

    // transpose out: thread (rr,cq) writes float4 at S2[(o<<8)+row][dstart+cq*4]
    int rr = threadIdx.x >> 3;              // 0..31
    int cq = threadIdx.x & 7;               // 0..7
#pragma unroll
    for (int it = 0; it < 8; ++it) {
        int row = it * 32 + rr;
        float4 v;
        v.x = Ls[row][cq * 4 + 0];
        v.y = Ls[row][cq * 4 + 1];
        v.z = Ls[row][cq * 4 + 2];
        v.w = Ls[row][cq * 4 + 3];
        *(float4*)&S2[(size_t)((o << 8) + row) * D_DIM + dstart + cq * 4] = v;
    }
}

// ---------- K5: out = (xbf @ WqT^T) * S2 — bf16 GEMM, 2-phase LDS dbuf ----------
__global__ __launch_bounds__(256) void k_qgemm(const ushort* __restrict__ xbf,
                                               const ushort* __restrict__ WqT,
                                               const float* __restrict__ S2,
                                               float* __restrict__ out) {
    __shared__ ushort As[2][8 * 128 * 8];   // 2 x 16 KB  [kk][row][8]
    __shared__ ushort Bs[2][8 * 128 * 8];   // 2 x 16 KB
    int bid = blockIdx.x;
    int mb = bid >> 1;           // 0..255  (M tile)
    int nb = bid & 1;            // 0..1    (N tile)
    int tid = threadIdx.x;
    int lane = tid & 63, w = tid >> 6;
    int wr = w >> 1, wc = w & 1;
    int l31 = lane & 31, lh = lane >> 5;

    f32x16 acc[2][2];
#pragma unroll
    for (int i = 0; i < 2; ++i)
#pragma unroll
        for (int j = 0; j < 2; ++j)
#pragma unroll
            for (int e = 0; e < 16; ++e) acc[i][j][e] = 0.f;

    const ushort* ab = xbf + (size_t)mb * 128 * D_DIM;
    const ushort* bb = WqT + (size_t)nb * 128 * D_DIM;

#define STAGE(buf, kb)                                                        \
    do {                                                                      \
        _Pragma("unroll")                                                     \
        for (int i = 0; i < 4; ++i) {                                         \
            int slot = i * 256 + tid;            /* 0..1023 = kk*128 + row */ \
            int kk = slot >> 7;                                               \
            int row = slot & 127;                                             \
            int ldsbase = (i * 256 + w * 64) * 8; /* wave-uniform base */     \
            gload_lds16(ab + (size_t)row * D_DIM + (kb) * 64 + kk * 8,        \
                        &As[buf][ldsbase]);                                   \
            gload_lds16(bb + (size_t)row * D_DIM + (kb) * 64 + kk * 8,        \
                        &Bs[buf][ldsbase]);                                   \
        }                                                                     \
    } while (0)

    STAGE(0, 0);
    __syncthreads();   // drains vmcnt(0): buf0 staged

#pragma unroll
    for (int kb = 0; kb < 4; ++kb) {
        int cur = kb & 1;
        if (kb < 3) STAGE(cur ^ 1, kb + 1);  // overlap next-tile loads w/ MFMA
#pragma unroll
        for (int s = 0; s < 4; ++s) {
            int c0 = (s * 2 + lh) * 128;
            bf16x8 a0 = *(bf16x8*)&As[cur][(c0 + wr * 64 + l31) * 8];
            bf16x8 a1 = *(bf16x8*)&As[cur][(c0 + wr * 64 + 32 + l31) * 8];
            bf16x8 b0 = *(bf16x8*)&Bs[cur][(c0 + wc * 64 + l31) * 8];
            bf16x8 b1 = *(bf16x8*)&Bs[cur][(c0 + wc * 64 + 32 + l31) * 8];
            acc[0][0] = __builtin_amdgcn_mfma_f32_32x32x16_bf16(a0, b0, acc[0][0], 0, 0, 0);
            acc[0][1] = __builtin_amdgcn_mfma_f32_32x32x16_bf16(a0, b1, acc[0][1], 0, 0, 0);
            acc[1][0] = __builtin_amdgcn_mfma_f32_32x32x16_bf16(a1, b0, acc[1][0], 0, 0, 0);
            acc[1][1] = __builtin_amdgcn_mfma_f32_32x32x16_bf16(a1, b1, acc[1][1], 0, 0, 0);
        }
        if (kb < 3) __syncthreads();  // one barrier/K-step: next buf staged + all reads done
    }
#undef STAGE

    int t_base = (mb & 15) * 128;
    size_t row_base = (size_t)mb * 128;
#pragma unroll
    for (int mi = 0; mi < 2; ++mi) {
#pragma unroll
        for (int ni = 0; ni < 2; ++ni) {
            int gn = nb * 128 + wc * 64 + ni * 32 + l31;
#pragma unroll
            for (int reg = 0; reg < 16; ++reg) {
                int rr = (reg & 3) + 8 * (reg >> 2) + 4 * lh;
                int m = wr * 64 + mi * 32 + rr;
                float s2v = S2[(size_t)(t_base + m) * D_DIM + gn];
                out[(row_base + m) * D_DIM + gn] = acc[mi][ni][reg] * s2v;
            }
        }
    }
}

extern "C" void kernel_launch(void* const* d_in, const int* in_sizes, int n_in,
                              void* d_out, int out_size, void* d_ws, size_t ws_size,
                              hipStream_t stream) {
    const float* x  = (const float*)d_in[0];
    const float* Wq = (const float*)d_in[1];
    const float* Wk = (const float*)d_in[2];
    const float* Wv = (const float*)d_in[3];
    float* out = (float*)d_out;

    // workspace layout
    float* ws = (float*)d_ws;
    float* loc    = ws;                        // 524288 f
    float* S2     = loc + 524288;              // 524288 f
    float* wv_sum = S2 + 524288;               // 256 f
    float* carry  = wv_sum + 256;              // 65536 f (256 chunks x 256)
    ushort* WqT   = (ushort*)(carry + 65536);  // 65536 us
    ushort* WkT   = WqT + 65536;               // 65536 us
    ushort* ybf   = WkT + 65536;               // 524288 us
    ushort* xbf   = ybf + 524288;              // 8388608 us (16 MB)

    k_prep<<<36, 256, 0, stream>>>(Wq, Wk, Wv, WqT, WkT, wv_sum);
    k_y<<<T_LEN / 4, 256, 0, stream>>>(x, wv_sum, ybf, xbf);
    k_gs<<<128, 256, 0, stream>>>(ybf, WkT, loc, carry);
    k_S2P<<<64, 256, 0, stream>>>(loc, carry, S2);
    k_qgemm<<<(B_DIM * T_LEN / 128) * 2, 256, 0, stream>>>(xbf, WqT, S2, out);
}